// Round 1
// baseline (3335.304 us; speedup 1.0000x reference)
//
#include <hip/hip_runtime.h>

#define HH 1024
#define WW 1024
#define NPIX (HH * WW)
#define NITER 100
#define THRESH_SQ 1e-8f
#define BOUNDARY_F 0.1f

__device__ __forceinline__ float wfun(float c, float n, float valid) {
    // same = (c>0.1) XOR (n>0.1); diff = c - n + same; w = exp(-|diff|) * valid
    float same = ((c > BOUNDARY_F) != (n > BOUNDARY_F)) ? 1.0f : 0.0f;
    float diff = c - n + same;
    return valid * __expf(-fabsf(diff));
}

__global__ void rw_init_kernel(const int* __restrict__ seeds,
                               float2* __restrict__ xe,
                               unsigned char* __restrict__ mask,
                               float* __restrict__ norms) {
    int idx = blockIdx.x * blockDim.x + threadIdx.x;
    if (idx < NPIX) {
        int s = seeds[idx];
        mask[idx] = (unsigned char)(s > 0);
        xe[idx] = make_float2(s == 1 ? 1.0f : 0.0f, s == 2 ? 1.0f : 0.0f);
    }
    if (blockIdx.x == 0 && threadIdx.x < 128) norms[threadIdx.x] = 0.0f;
}

// Each thread handles a horizontal pair of pixels (j even, j+1).
__launch_bounds__(256)
__global__ void rw_update_kernel(const float* __restrict__ img,
                                 const unsigned char* __restrict__ mask,
                                 const float2* __restrict__ xin,
                                 float2* __restrict__ xout,
                                 float* __restrict__ norms,
                                 int k) {
    __shared__ int   s_hit[4];
    __shared__ float s_part[4];
    const int tid = threadIdx.x;
    const int gid = blockIdx.x * 256 + tid;   // pair index
    const int wv = tid >> 6;

    // done = OR over s<k of (norms[s] < 1e-8): parallel scan + ballot
    bool hit = (tid < k) && (norms[tid] < THRESH_SQ);
    unsigned long long b = __ballot(hit ? 1 : 0);
    if ((tid & 63) == 0) s_hit[wv] = (b != 0ull) ? 1 : 0;
    __syncthreads();
    const bool done = (s_hit[0] | s_hit[1] | s_hit[2] | s_hit[3]) != 0;

    const float4* __restrict__ xin4 = (const float4*)xin;
    float4* __restrict__ xout4 = (float4*)xout;
    float4 xc = xin4[gid];

    if (done) {             // frozen: pure copy (block-uniform branch)
        xout4[gid] = xc;
        return;
    }

    const int p = gid * 2;          // first pixel index of the pair
    const int i = p >> 10;
    const int j = p & 1023;

    // neighbor addresses, clamped in-bounds (invalid dirs get weight 0)
    const int upP = (i > 0)      ? gid - (WW / 2) : gid;
    const int dnP = (i < HH - 1) ? gid + (WW / 2) : gid;
    float4 xu = xin4[upP];
    float4 xd = xin4[dnP];
    float2 xl = xin[(j > 0) ? p - 1 : p];
    float2 xr = xin[(j < WW - 2) ? p + 2 : p + 1];

    const float2* __restrict__ img2 = (const float2*)img;
    float2 c  = img2[gid];
    float2 iu = img2[upP];
    float2 id = img2[dnP];
    float il = img[(j > 0) ? p - 1 : p];
    float ir = img[(j < WW - 2) ? p + 2 : p + 1];

    const float vU  = (i > 0) ? 1.0f : 0.0f;
    const float vD  = (i < HH - 1) ? 1.0f : 0.0f;
    const float vL0 = (j > 0) ? 1.0f : 0.0f;
    const float vR1 = (j < WW - 2) ? 1.0f : 0.0f;

    // pixel 0 weights (dirs: up, down, left, right)
    float w0u = wfun(c.x, iu.x, vU);
    float w0d = wfun(c.x, id.x, vD);
    float w0l = wfun(c.x, il,   vL0);
    float w0r = wfun(c.x, c.y,  1.0f);
    float rs0 = w0u + w0d + w0l + w0r;
    float inv0 = (rs0 > 0.0f) ? 1.0f / rs0 : 0.0f;

    // pixel 1 weights
    float w1u = wfun(c.y, iu.y, vU);
    float w1d = wfun(c.y, id.y, vD);
    float w1l = wfun(c.y, c.x,  1.0f);
    float w1r = wfun(c.y, ir,   vR1);
    float rs1 = w1u + w1d + w1l + w1r;
    float inv1 = (rs1 > 0.0f) ? 1.0f / rs1 : 0.0f;

    unsigned short mm = ((const unsigned short*)mask)[gid];
    const bool m0 = (mm & 0xff) != 0;
    const bool m1 = (mm >> 8) != 0;

    float n0x = inv0 * (w0u * xu.x + w0d * xd.x + w0l * xl.x + w0r * xc.z);
    float n0y = inv0 * (w0u * xu.y + w0d * xd.y + w0l * xl.y + w0r * xc.w);
    float n1x = inv1 * (w1u * xu.z + w1d * xd.z + w1l * xc.x + w1r * xr.x);
    float n1y = inv1 * (w1u * xu.w + w1d * xd.w + w1l * xc.y + w1r * xr.y);

    float4 out;
    out.x = m0 ? xc.x : n0x;
    out.y = m0 ? xc.y : n0y;
    out.z = m1 ? xc.z : n1x;
    out.w = m1 ? xc.w : n1y;
    xout4[gid] = out;

    // squared-delta reduction -> norms[k]
    float dx = out.x - xc.x, dy = out.y - xc.y;
    float dz = out.z - xc.z, dw = out.w - xc.w;
    float sq = dx * dx + dy * dy + dz * dz + dw * dw;
#pragma unroll
    for (int off = 32; off > 0; off >>= 1) sq += __shfl_down(sq, off, 64);
    if ((tid & 63) == 0) s_part[wv] = sq;
    __syncthreads();
    if (tid == 0) {
        float tot = s_part[0] + s_part[1] + s_part[2] + s_part[3];
        atomicAdd(&norms[k], tot);
    }
}

extern "C" void kernel_launch(void* const* d_in, const int* in_sizes, int n_in,
                              void* d_out, int out_size, void* d_ws, size_t ws_size,
                              hipStream_t stream) {
    const float* img  = (const float*)d_in[0];
    const int* seeds  = (const int*)d_in[1];

    // x even buffer lives in d_out (final iter 100 lands there), odd buffer in ws
    float2* xe = (float2*)d_out;
    char* ws = (char*)d_ws;
    float2* xo = (float2*)ws;                                         // 8 MB
    unsigned char* mask = (unsigned char*)(ws + 8ull * 1024 * 1024);  // 1 MB
    float* norms = (float*)(ws + 9ull * 1024 * 1024);                 // 512 B

    rw_init_kernel<<<NPIX / 256, 256, 0, stream>>>(seeds, xe, mask, norms);

    for (int t = 1; t <= NITER; ++t) {
        const float2* xin = (t & 1) ? (const float2*)xe : (const float2*)xo;
        float2* xout      = (t & 1) ? xo : xe;
        rw_update_kernel<<<NPIX / 512, 256, 0, stream>>>(img, mask, xin, xout, norms, t - 1);
    }
}

// Round 3
// 3195.360 us; speedup vs baseline: 1.0438x; 1.0438x over previous
//
#include <hip/hip_runtime.h>

#define HH 1024
#define WW 1024
#define NPAIRS (HH * WW / 2)       // 524288 horizontal pixel pairs
#define TPB 256
#define NBLK 256                   // 1 block/CU guaranteed resident -> safe sw barrier
#define BANDP 2048                 // pairs per block (4 rows)
#define NCHUNK 8                   // BANDP / TPB
#define NITER 100
#define THRESH_SQ 1e-8f
#define BOUNDARY_F 0.1f

__device__ __forceinline__ float wfun(float c, float n, float valid) {
    float same = ((c > BOUNDARY_F) != (n > BOUNDARY_F)) ? 1.0f : 0.0f;
    return valid * __expf(-fabsf(c - n + same));
}

__global__ void rw_init_kernel(const int* __restrict__ seeds,
                               float2* __restrict__ xA,
                               unsigned char* __restrict__ mask,
                               float* __restrict__ norms,
                               unsigned* __restrict__ bar) {
    int P = blockIdx.x * blockDim.x + threadIdx.x;   // pair index
    if (P < NPAIRS) {
        const int2* seeds2 = (const int2*)seeds;
        int2 s = seeds2[P];
        ((unsigned short*)mask)[P] =
            (unsigned short)((s.x > 0 ? 1 : 0) | (s.y > 0 ? 0x100 : 0));
        float4 v;
        v.x = (s.x == 1) ? 1.0f : 0.0f;
        v.y = (s.x == 2) ? 1.0f : 0.0f;
        v.z = (s.y == 1) ? 1.0f : 0.0f;
        v.w = (s.y == 2) ? 1.0f : 0.0f;
        ((float4*)xA)[P] = v;
    }
    if (blockIdx.x == 0 && threadIdx.x < 128) {
        norms[threadIdx.x] = 0.0f;
        bar[threadIdx.x] = 0u;
    }
}

// Grid barrier instance t: arrive (release) + spin (acquire). Counters are
// single-use per iteration, so no reset race. Guard bounds the spin so a
// co-residency failure degrades to a wrong answer, not a hang.
__device__ __forceinline__ void gbar(unsigned* __restrict__ bar, int t) {
    __syncthreads();
    if (threadIdx.x == 0) {
        __threadfence();
        __hip_atomic_fetch_add(&bar[t], 1u, __ATOMIC_RELEASE,
                               __HIP_MEMORY_SCOPE_AGENT);
        int guard = 0;
        while (__hip_atomic_load(&bar[t], __ATOMIC_ACQUIRE,
                                 __HIP_MEMORY_SCOPE_AGENT) < (unsigned)NBLK) {
            __builtin_amdgcn_s_sleep(2);
            if (++guard > (1 << 22)) break;
        }
    }
    __syncthreads();
}

__launch_bounds__(TPB, 1)
__global__ void rw_persist_kernel(const float* __restrict__ img,
                                  const unsigned char* __restrict__ mask,
                                  float2* __restrict__ xA,
                                  float2* __restrict__ xB,
                                  float* __restrict__ norms,
                                  unsigned* __restrict__ bar) {
    const int tid = threadIdx.x;
    // XCD swizzle: adjacent bands share an XCD (32 contiguous bands per XCD)
    const int band = ((blockIdx.x & 7) << 5) | (blockIdx.x >> 3);
    const int base = band * BANDP;
    __shared__ float s_part[TPB / 64];

    const float2* img2 = (const float2*)img;
    const unsigned short* mask16 = (const unsigned short*)mask;

    bool done = false;

    for (int t = 0; t < NITER; ++t) {
        const float2* xin  = (t & 1) ? (const float2*)xB : (const float2*)xA;
        float2*       xout = (t & 1) ? xA : xB;
        const float4* xin4 = (const float4*)xin;
        float4*      xout4 = (float4*)xout;

        if (!done) {
            float sq = 0.0f;
#pragma unroll
            for (int c = 0; c < NCHUNK; ++c) {
                const int P = base + c * TPB + tid;  // pair index
                const int p = P * 2;                 // pixel index
                const int i = p >> 10;
                const int j = p & 1023;

                const int upP = (i > 0)      ? P - (WW / 2) : P;
                const int dnP = (i < HH - 1) ? P + (WW / 2) : P;

                float4 xc = xin4[P];
                float4 xu = xin4[upP];
                float4 xd = xin4[dnP];
                float2 xl = xin[(j > 0) ? p - 1 : p];
                float2 xr = xin[(j < WW - 2) ? p + 2 : p + 1];

                float2 cc = img2[P];
                float2 iu = img2[upP];
                float2 id = img2[dnP];
                float  il = img[(j > 0) ? p - 1 : p];
                float  ir = img[(j < WW - 2) ? p + 2 : p + 1];

                const float vU  = (i > 0) ? 1.0f : 0.0f;
                const float vD  = (i < HH - 1) ? 1.0f : 0.0f;
                const float vL0 = (j > 0) ? 1.0f : 0.0f;
                const float vR1 = (j < WW - 2) ? 1.0f : 0.0f;

                float w0u = wfun(cc.x, iu.x, vU);
                float w0d = wfun(cc.x, id.x, vD);
                float w0l = wfun(cc.x, il,   vL0);
                float w0r = wfun(cc.x, cc.y, 1.0f);
                float rs0 = w0u + w0d + w0l + w0r;
                float inv0 = (rs0 > 0.0f) ? 1.0f / rs0 : 0.0f;

                float w1u = wfun(cc.y, iu.y, vU);
                float w1d = wfun(cc.y, id.y, vD);
                float w1l = wfun(cc.y, cc.x, 1.0f);
                float w1r = wfun(cc.y, ir,   vR1);
                float rs1 = w1u + w1d + w1l + w1r;
                float inv1 = (rs1 > 0.0f) ? 1.0f / rs1 : 0.0f;

                unsigned short mm = mask16[P];
                const bool m0 = (mm & 0xff) != 0;
                const bool m1 = (mm >> 8) != 0;

                float n0x = inv0 * (w0u * xu.x + w0d * xd.x + w0l * xl.x + w0r * xc.z);
                float n0y = inv0 * (w0u * xu.y + w0d * xd.y + w0l * xl.y + w0r * xc.w);
                float n1x = inv1 * (w1u * xu.z + w1d * xd.z + w1l * xc.x + w1r * xr.x);
                float n1y = inv1 * (w1u * xu.w + w1d * xd.w + w1l * xc.y + w1r * xr.y);

                float4 out;
                out.x = m0 ? xc.x : n0x;
                out.y = m0 ? xc.y : n0y;
                out.z = m1 ? xc.z : n1x;
                out.w = m1 ? xc.w : n1y;
                xout4[P] = out;

                float dx = out.x - xc.x, dy = out.y - xc.y;
                float dz = out.z - xc.z, dw = out.w - xc.w;
                sq += dx * dx + dy * dy + dz * dz + dw * dw;
            }
            if (t < NITER - 1) {
#pragma unroll
                for (int off = 32; off > 0; off >>= 1)
                    sq += __shfl_down(sq, off, 64);
                if ((tid & 63) == 0) s_part[tid >> 6] = sq;
                __syncthreads();
                if (tid == 0)
                    atomicAdd(&norms[t],
                              s_part[0] + s_part[1] + s_part[2] + s_part[3]);
            }
        } else {
            // frozen: copy (keeps ping-pong parity so iter 100 lands in xA)
#pragma unroll
            for (int c = 0; c < NCHUNK; ++c) {
                int P = base + c * TPB + tid;
                xout4[P] = xin4[P];
            }
        }

        if (t == NITER - 1) break;   // uniform exit, no final barrier needed
        gbar(bar, t);
        done = done ||
               (__hip_atomic_load(&norms[t], __ATOMIC_RELAXED,
                                  __HIP_MEMORY_SCOPE_AGENT) < THRESH_SQ);
    }
}

extern "C" void kernel_launch(void* const* d_in, const int* in_sizes, int n_in,
                              void* d_out, int out_size, void* d_ws, size_t ws_size,
                              hipStream_t stream) {
    const float* img = (const float*)d_in[0];
    const int* seeds = (const int*)d_in[1];

    float2* xA = (float2*)d_out;                                      // final buffer
    char* ws = (char*)d_ws;
    float2* xB = (float2*)ws;                                         // 8 MB
    unsigned char* mask = (unsigned char*)(ws + 8ull * 1024 * 1024);  // 1 MB
    float* norms = (float*)(ws + 9ull * 1024 * 1024);                 // 512 B
    unsigned* bar = (unsigned*)(ws + 9ull * 1024 * 1024 + 512);       // 512 B

    rw_init_kernel<<<NPAIRS / TPB, TPB, 0, stream>>>(seeds, xA, mask, norms, bar);
    rw_persist_kernel<<<NBLK, TPB, 0, stream>>>(img, mask, xA, xB, norms, bar);
}

// Round 4
// 2080.467 us; speedup vs baseline: 1.6032x; 1.5359x over previous
//
#include <hip/hip_runtime.h>

#define HH 1024
#define WW 1024
#define NPAIRS (HH * WW / 2)       // 524288 horizontal pixel pairs
#define TPB 256
#define NBLK 512                   // 2 blocks/CU, guaranteed by __launch_bounds__(256,2)
#define NCHUNK 4                   // pairs per thread; band = 1024 pairs = 2 rows
#define NITER 100
#define THRESH_SQ 1e-8f
#define BOUNDARY_F 0.1f
#define NGRP 8
#define BLKPG (NBLK / NGRP)        // 64 blocks per barrier group
#define SLOT 32                    // dwords per barrier slot (128 B, own cache line)

// barrier region layout (dword offsets)
#define OFF_SQ    0                              // [NITER][NBLK] float
#define OFF_NPART (OFF_SQ + NITER * NBLK)        // [NITER][NGRP] float, stride SLOT
#define OFF_GCNT  (OFF_NPART + NITER * NGRP * SLOT)
#define OFF_RCNT  (OFF_GCNT + NITER * NGRP * SLOT)
#define OFF_GO    (OFF_RCNT + NITER * SLOT)
#define BAR_DWORDS (OFF_GO + NITER * SLOT)       // 108800 dwords = 425 KB

__device__ __forceinline__ float wfun(float c, float n, float valid) {
    float same = ((c > BOUNDARY_F) != (n > BOUNDARY_F)) ? 1.0f : 0.0f;
    return valid * __expf(-fabsf(c - n + same));
}

__global__ void rw_init_kernel(const int* __restrict__ seeds,
                               float2* __restrict__ xA,
                               unsigned* __restrict__ bar) {
    int P = blockIdx.x * blockDim.x + threadIdx.x;   // pair index
    if (P < NPAIRS) {
        const int2* seeds2 = (const int2*)seeds;
        int2 s = seeds2[P];
        float4 v;
        v.x = (s.x == 1) ? 1.0f : 0.0f;
        v.y = (s.x == 2) ? 1.0f : 0.0f;
        v.z = (s.y == 1) ? 1.0f : 0.0f;
        v.w = (s.y == 2) ? 1.0f : 0.0f;
        ((float4*)xA)[P] = v;
    }
    int gid = blockIdx.x * blockDim.x + threadIdx.x;
    if (gid < BAR_DWORDS) bar[gid] = 0u;
}

__launch_bounds__(TPB, 2)
__global__ void rw_persist_kernel(const float* __restrict__ img,
                                  const int* __restrict__ seeds,
                                  float2* __restrict__ xA,
                                  float2* __restrict__ xB,
                                  unsigned* __restrict__ bar) {
    const int tid = threadIdx.x;
    const int blk = blockIdx.x;
    // XCD swizzle (perf only): XCD r (blk%8) owns bands r*64 .. r*64+63
    const int band = ((blk & 7) << 6) | (blk >> 3);
    const int base = band * (TPB * NCHUNK);
    __shared__ float s_part[TPB / 64];
    __shared__ unsigned s_go;

    float* sq_arr   = (float*)bar + OFF_SQ;
    float* npart    = (float*)bar + OFF_NPART;
    unsigned* gcnt  = bar + OFF_GCNT;
    unsigned* rcnt  = bar + OFF_RCNT;
    unsigned* go    = bar + OFF_GO;

    // ---- precompute folded transition coefficients (iteration-invariant) ----
    int Pp[NCHUNK], Pu[NCHUNK], Pd[NCHUNK], Pl[NCHUNK], Pr[NCHUNK];
    float cf[NCHUNK][10];
    {
        const float2* img2 = (const float2*)img;
        const int2* seeds2 = (const int2*)seeds;
#pragma unroll
        for (int c = 0; c < NCHUNK; ++c) {
            const int P = base + c * TPB + tid;
            const int p = P * 2;
            const int i = p >> 10;
            const int j = p & 1023;
            const int uP = (i > 0) ? P - (WW / 2) : P;
            const int dP = (i < HH - 1) ? P + (WW / 2) : P;
            const int lp = (j > 0) ? p - 1 : p;
            const int rp = (j < WW - 2) ? p + 2 : p + 1;
            Pp[c] = P; Pu[c] = uP; Pd[c] = dP; Pl[c] = lp; Pr[c] = rp;

            float2 cc = img2[P], iu = img2[uP], id = img2[dP];
            float il = img[lp], ir = img[rp];
            const float vU = (i > 0) ? 1.0f : 0.0f;
            const float vD = (i < HH - 1) ? 1.0f : 0.0f;
            const float vL = (j > 0) ? 1.0f : 0.0f;
            const float vR = (j < WW - 2) ? 1.0f : 0.0f;

            float w0u = wfun(cc.x, iu.x, vU), w0d = wfun(cc.x, id.x, vD);
            float w0l = wfun(cc.x, il, vL),   w0r = wfun(cc.x, cc.y, 1.0f);
            float rs0 = w0u + w0d + w0l + w0r;
            float inv0 = (rs0 > 0.0f) ? 1.0f / rs0 : 0.0f;
            float w1u = wfun(cc.y, iu.y, vU), w1d = wfun(cc.y, id.y, vD);
            float w1l = wfun(cc.y, cc.x, 1.0f), w1r = wfun(cc.y, ir, vR);
            float rs1 = w1u + w1d + w1l + w1r;
            float inv1 = (rs1 > 0.0f) ? 1.0f / rs1 : 0.0f;

            int2 s = seeds2[P];
            const bool m0 = s.x > 0, m1 = s.y > 0;
            cf[c][0] = m0 ? 0.0f : w0u * inv0;
            cf[c][1] = m0 ? 0.0f : w0d * inv0;
            cf[c][2] = m0 ? 0.0f : w0l * inv0;
            cf[c][3] = m0 ? 0.0f : w0r * inv0;
            cf[c][4] = m0 ? 1.0f : 0.0f;          // self weight (absorbing seed)
            cf[c][5] = m1 ? 0.0f : w1u * inv1;
            cf[c][6] = m1 ? 0.0f : w1d * inv1;
            cf[c][7] = m1 ? 0.0f : w1l * inv1;
            cf[c][8] = m1 ? 0.0f : w1r * inv1;
            cf[c][9] = m1 ? 1.0f : 0.0f;
        }
    }

    bool done = false;

    for (int t = 0; t < NITER; ++t) {
        const float2* xin  = (t & 1) ? (const float2*)xB : (const float2*)xA;
        float2*       xout = (t & 1) ? xA : xB;
        const float4* xin4 = (const float4*)xin;
        float4*      xout4 = (float4*)xout;

        float sq = 0.0f;
        if (!done) {
#pragma unroll
            for (int c = 0; c < NCHUNK; ++c) {
                float4 xc = xin4[Pp[c]];
                float4 xu = xin4[Pu[c]];
                float4 xd = xin4[Pd[c]];
                float2 xl = xin[Pl[c]];
                float2 xr = xin[Pr[c]];
                float4 out;
                out.x = cf[c][0]*xu.x + cf[c][1]*xd.x + cf[c][2]*xl.x + cf[c][3]*xc.z + cf[c][4]*xc.x;
                out.y = cf[c][0]*xu.y + cf[c][1]*xd.y + cf[c][2]*xl.y + cf[c][3]*xc.w + cf[c][4]*xc.y;
                out.z = cf[c][5]*xu.z + cf[c][6]*xd.z + cf[c][7]*xc.x + cf[c][8]*xr.x + cf[c][9]*xc.z;
                out.w = cf[c][5]*xu.w + cf[c][6]*xd.w + cf[c][7]*xc.y + cf[c][8]*xr.y + cf[c][9]*xc.w;
                xout4[Pp[c]] = out;
                float dx = out.x - xc.x, dy = out.y - xc.y;
                float dz = out.z - xc.z, dw = out.w - xc.w;
                sq += dx * dx + dy * dy + dz * dz + dw * dw;
            }
        } else {
            // frozen: copy (keeps ping-pong parity so iter 100 lands in xA)
#pragma unroll
            for (int c = 0; c < NCHUNK; ++c) xout4[Pp[c]] = xin4[Pp[c]];
        }

        if (t == NITER - 1) break;   // no barrier needed after the last step

        // block-level reduce of sq
#pragma unroll
        for (int off = 32; off > 0; off >>= 1) sq += __shfl_down(sq, off, 64);
        if ((tid & 63) == 0) s_part[tid >> 6] = sq;
        __syncthreads();             // also drains this block's xout stores

        if (tid == 0) {
            const int g = blk >> 6;  // barrier group 0..7
            float blocksq = s_part[0] + s_part[1] + s_part[2] + s_part[3];
            // deposit norm contribution (plain coherent store, no RMW)
            __hip_atomic_store(&sq_arr[t * NBLK + blk], blocksq,
                               __ATOMIC_RELAXED, __HIP_MEMORY_SCOPE_AGENT);
            // release: flush this XCD's dirty L2 (xout + sq slot) once per block
            __builtin_amdgcn_fence(__ATOMIC_RELEASE, "agent");
            unsigned n = atomicAdd(&gcnt[(t * NGRP + g) * SLOT], 1u);
            if (n == BLKPG - 1) {
                // last of group: sum the group's 64 slots
                float s = 0.0f;
#pragma unroll 8
                for (int k = 0; k < BLKPG; ++k)
                    s += __hip_atomic_load(&sq_arr[t * NBLK + g * BLKPG + k],
                                           __ATOMIC_RELAXED, __HIP_MEMORY_SCOPE_AGENT);
                __hip_atomic_store(&npart[(t * NGRP + g) * SLOT], s,
                                   __ATOMIC_RELAXED, __HIP_MEMORY_SCOPE_AGENT);
                __builtin_amdgcn_s_waitcnt(0);   // npart store globally visible
                unsigned m = atomicAdd(&rcnt[t * SLOT], 1u);
                if (m == NGRP - 1) {
                    float tot = 0.0f;
#pragma unroll
                    for (int gg = 0; gg < NGRP; ++gg)
                        tot += __hip_atomic_load(&npart[(t * NGRP + gg) * SLOT],
                                                 __ATOMIC_RELAXED, __HIP_MEMORY_SCOPE_AGENT);
                    __hip_atomic_store(&go[t * SLOT],
                                       (tot < THRESH_SQ) ? 2u : 1u,
                                       __ATOMIC_RELAXED, __HIP_MEMORY_SCOPE_AGENT);
                }
            }
            // spin with RELAXED loads (no cache ops per poll)
            unsigned v = 0;
            int guard = 0;
            do {
                v = __hip_atomic_load(&go[t * SLOT], __ATOMIC_RELAXED,
                                      __HIP_MEMORY_SCOPE_AGENT);
                if (v) break;
                __builtin_amdgcn_s_sleep(1);
            } while (++guard < (1 << 18));
            if (!v) v = 1u;
            // single acquire per block per iteration: invalidate stale L1/L2
            __builtin_amdgcn_fence(__ATOMIC_ACQUIRE, "agent");
            s_go = v;
        }
        __syncthreads();
        done = done || (s_go == 2u);
    }
}

extern "C" void kernel_launch(void* const* d_in, const int* in_sizes, int n_in,
                              void* d_out, int out_size, void* d_ws, size_t ws_size,
                              hipStream_t stream) {
    const float* img = (const float*)d_in[0];
    const int* seeds = (const int*)d_in[1];

    float2* xA = (float2*)d_out;                                // final buffer
    char* ws = (char*)d_ws;
    float2* xB = (float2*)ws;                                   // 8 MB
    unsigned* bar = (unsigned*)(ws + 8ull * 1024 * 1024);       // ~425 KB

    rw_init_kernel<<<NPAIRS / TPB, TPB, 0, stream>>>(seeds, xA, bar);
    rw_persist_kernel<<<NBLK, TPB, 0, stream>>>(img, seeds, xA, xB, bar);
}

// Round 5
// 1000.823 us; speedup vs baseline: 3.3326x; 2.0788x over previous
//
#include <hip/hip_runtime.h>

typedef unsigned long long u64;

#define HH 1024
#define WW 1024
#define NPAIRS (HH * WW / 2)       // 524288 horizontal pixel pairs
#define TPB 256
#define NBLK 512                   // 2 blocks/CU via __launch_bounds__(256,2)
#define NCHUNK 4                   // band = 1024 pairs = 2 rows
#define NITER 100
#define THRESH_SQ 1e-8f
#define BOUNDARY_F 0.1f
#define NGRP 8
#define BLKPG (NBLK / NGRP)
#define SLOT 32                    // dwords per slot (128 B line)

#define OFF_SQ    0                              // [NITER][NBLK] float
#define OFF_NPART (OFF_SQ + NITER * NBLK)
#define OFF_GCNT  (OFF_NPART + NITER * NGRP * SLOT)
#define OFF_RCNT  (OFF_GCNT + NITER * NGRP * SLOT)
#define OFF_GO    (OFF_RCNT + NITER * SLOT)
#define BAR_DWORDS (OFF_GO + NITER * SLOT)

union f2u { u64 u; float2 f; };

__device__ __forceinline__ float2 cld(const u64* p) {   // coherent (sc1) 8B load
    f2u t;
    t.u = __hip_atomic_load(p, __ATOMIC_RELAXED, __HIP_MEMORY_SCOPE_AGENT);
    return t.f;
}
__device__ __forceinline__ void cst(u64* p, float a, float b) {  // coherent 8B store
    f2u t; t.f = make_float2(a, b);
    __hip_atomic_store(p, t.u, __ATOMIC_RELAXED, __HIP_MEMORY_SCOPE_AGENT);
}

__device__ __forceinline__ float wfun(float c, float n, float valid) {
    float same = ((c > BOUNDARY_F) != (n > BOUNDARY_F)) ? 1.0f : 0.0f;
    return valid * __expf(-fabsf(c - n + same));
}

__global__ void rw_init_kernel(const int* __restrict__ seeds,
                               float2* __restrict__ xA,
                               unsigned* __restrict__ bar) {
    int P = blockIdx.x * blockDim.x + threadIdx.x;
    if (P < NPAIRS) {
        int2 s = ((const int2*)seeds)[P];
        float4 v;
        v.x = (s.x == 1) ? 1.0f : 0.0f;
        v.y = (s.x == 2) ? 1.0f : 0.0f;
        v.z = (s.y == 1) ? 1.0f : 0.0f;
        v.w = (s.y == 2) ? 1.0f : 0.0f;
        ((float4*)xA)[P] = v;
    }
    if (P < BAR_DWORDS) bar[P] = 0u;
}

__launch_bounds__(TPB, 2)
__global__ void rw_persist_kernel(const float* __restrict__ img,
                                  const int* __restrict__ seeds,
                                  float2* __restrict__ xA,
                                  float2* __restrict__ xB,
                                  unsigned* __restrict__ bar) {
    const int tid = threadIdx.x;
    const int blk = blockIdx.x;
    const int band = ((blk & 7) << 6) | (blk >> 3);   // XCD swizzle (perf only)
    const int base = band * (TPB * NCHUNK);           // first pair of band
    const int i0 = band * 2;                          // first row of band

    __shared__ float4 tile[2048];     // [0,1024) band, [1024,1536) up-halo, [1536,2048) down-halo
    __shared__ float s_part[TPB / 64];
    __shared__ unsigned s_go;

    float* sq_arr  = (float*)bar + OFF_SQ;
    float* npart   = (float*)bar + OFF_NPART;
    unsigned* gcnt = bar + OFF_GCNT;
    unsigned* rcnt = bar + OFF_RCNT;
    unsigned* go   = bar + OFF_GO;

    // ---- precompute folded transition coefficients (iteration-invariant) ----
    float cf[NCHUNK][10];
    {
        const float2* img2 = (const float2*)img;
        const int2* seeds2 = (const int2*)seeds;
#pragma unroll
        for (int c = 0; c < NCHUNK; ++c) {
            const int P = base + c * TPB + tid;
            const int p = P * 2;
            const int i = p >> 10;
            const int j = p & 1023;
            const int uP = (i > 0) ? P - (WW / 2) : P;
            const int dP = (i < HH - 1) ? P + (WW / 2) : P;
            const int lp = (j > 0) ? p - 1 : p;
            const int rp = (j < WW - 2) ? p + 2 : p + 1;

            float2 cc = img2[P], iu = img2[uP], id = img2[dP];
            float il = img[lp], ir = img[rp];
            const float vU = (i > 0) ? 1.0f : 0.0f;
            const float vD = (i < HH - 1) ? 1.0f : 0.0f;
            const float vL = (j > 0) ? 1.0f : 0.0f;
            const float vR = (j < WW - 2) ? 1.0f : 0.0f;

            float w0u = wfun(cc.x, iu.x, vU), w0d = wfun(cc.x, id.x, vD);
            float w0l = wfun(cc.x, il, vL),   w0r = wfun(cc.x, cc.y, 1.0f);
            float rs0 = w0u + w0d + w0l + w0r;
            float inv0 = (rs0 > 0.0f) ? 1.0f / rs0 : 0.0f;
            float w1u = wfun(cc.y, iu.y, vU), w1d = wfun(cc.y, id.y, vD);
            float w1l = wfun(cc.y, cc.x, 1.0f), w1r = wfun(cc.y, ir, vR);
            float rs1 = w1u + w1d + w1l + w1r;
            float inv1 = (rs1 > 0.0f) ? 1.0f / rs1 : 0.0f;

            int2 s = seeds2[P];
            const bool m0 = s.x > 0, m1 = s.y > 0;
            cf[c][0] = m0 ? 0.0f : w0u * inv0;
            cf[c][1] = m0 ? 0.0f : w0d * inv0;
            cf[c][2] = m0 ? 0.0f : w0l * inv0;
            cf[c][3] = m0 ? 0.0f : w0r * inv0;
            cf[c][4] = m0 ? 1.0f : 0.0f;
            cf[c][5] = m1 ? 0.0f : w1u * inv1;
            cf[c][6] = m1 ? 0.0f : w1d * inv1;
            cf[c][7] = m1 ? 0.0f : w1l * inv1;
            cf[c][8] = m1 ? 0.0f : w1r * inv1;
            cf[c][9] = m1 ? 1.0f : 0.0f;
        }
    }

    for (int t = 0; t < NITER; ++t) {
        const float4* xin4 = (t & 1) ? (const float4*)xB : (const float4*)xA;
        float4*      xout4 = (t & 1) ? (float4*)xA : (float4*)xB;

        // ---- stage band + halos into LDS via coherent loads ----
#pragma unroll
        for (int c = 0; c < NCHUNK; ++c) {
            int bp = c * TPB + tid;
            const u64* src = (const u64*)(xin4 + base + bp);
            float2 lo = cld(src), hi = cld(src + 1);
            tile[bp] = make_float4(lo.x, lo.y, hi.x, hi.y);
        }
        {
            const int rup = (band == 0) ? 0 : i0 - 1;          // unused values get cf=0
            const int rdn = (band == NBLK - 1) ? HH - 1 : i0 + 2;
#pragma unroll
            for (int c2 = 0; c2 < 2; ++c2) {
                int hp = c2 * TPB + tid;                       // 0..511
                const u64* su = (const u64*)(xin4 + rup * 512 + hp);
                float2 lo = cld(su), hi = cld(su + 1);
                tile[1024 + hp] = make_float4(lo.x, lo.y, hi.x, hi.y);
                const u64* sd = (const u64*)(xin4 + rdn * 512 + hp);
                lo = cld(sd); hi = cld(sd + 1);
                tile[1536 + hp] = make_float4(lo.x, lo.y, hi.x, hi.y);
            }
        }
        __syncthreads();

        // ---- compute from LDS, store coherently ----
        float sq = 0.0f;
        float4 outv[NCHUNK];
        const float2* t2 = (const float2*)tile;
#pragma unroll
        for (int c = 0; c < NCHUNK; ++c) {
            const int bp = c * TPB + tid;
            const int r = bp >> 9;            // 0 or 1 (row within band)
            const int jp = bp & 511;          // column pair
            float4 xc = tile[bp];
            float4 xu = r ? tile[jp] : tile[1024 + jp];
            float4 xd = r ? tile[1536 + jp] : tile[512 + jp];
            float2 xl = jp ? t2[2 * bp - 1] : t2[2 * bp];
            float2 xr = (jp < 511) ? t2[2 * bp + 2] : t2[2 * bp + 1];

            float4 out;
            out.x = cf[c][0]*xu.x + cf[c][1]*xd.x + cf[c][2]*xl.x + cf[c][3]*xc.z + cf[c][4]*xc.x;
            out.y = cf[c][0]*xu.y + cf[c][1]*xd.y + cf[c][2]*xl.y + cf[c][3]*xc.w + cf[c][4]*xc.y;
            out.z = cf[c][5]*xu.z + cf[c][6]*xd.z + cf[c][7]*xc.x + cf[c][8]*xr.x + cf[c][9]*xc.z;
            out.w = cf[c][5]*xu.w + cf[c][6]*xd.w + cf[c][7]*xc.y + cf[c][8]*xr.y + cf[c][9]*xc.w;
            outv[c] = out;

            u64* dst = (u64*)(xout4 + base + bp);
            cst(dst,     out.x, out.y);
            cst(dst + 1, out.z, out.w);

            float dx = out.x - xc.x, dy = out.y - xc.y;
            float dz = out.z - xc.z, dw = out.w - xc.w;
            sq += dx * dx + dy * dy + dz * dz + dw * dw;
        }

        if (t == NITER - 1) break;     // t=99 (odd) wrote xA = d_out; done

        // ---- block reduce of sq ----
#pragma unroll
        for (int off = 32; off > 0; off >>= 1) sq += __shfl_down(sq, off, 64);
        if ((tid & 63) == 0) s_part[tid >> 6] = sq;
        __syncthreads();               // also drains this block's sc1 stores (vmcnt 0)

        // ---- fence-free tree barrier (all traffic sc1-coherent) ----
        if (tid == 0) {
            const int g = blk >> 6;
            float blocksq = s_part[0] + s_part[1] + s_part[2] + s_part[3];
            __hip_atomic_store(&sq_arr[t * NBLK + blk], blocksq,
                               __ATOMIC_RELAXED, __HIP_MEMORY_SCOPE_AGENT);
            __builtin_amdgcn_s_waitcnt(0);   // sq store at coherence point
            unsigned n = __hip_atomic_fetch_add(&gcnt[(t * NGRP + g) * SLOT], 1u,
                                                __ATOMIC_RELAXED, __HIP_MEMORY_SCOPE_AGENT);
            if (n == BLKPG - 1) {
                float s = 0.0f;
#pragma unroll 8
                for (int k = 0; k < BLKPG; ++k)
                    s += __hip_atomic_load(&sq_arr[t * NBLK + g * BLKPG + k],
                                           __ATOMIC_RELAXED, __HIP_MEMORY_SCOPE_AGENT);
                __hip_atomic_store(&npart[(t * NGRP + g) * SLOT], s,
                                   __ATOMIC_RELAXED, __HIP_MEMORY_SCOPE_AGENT);
                __builtin_amdgcn_s_waitcnt(0);
                unsigned m = __hip_atomic_fetch_add(&rcnt[t * SLOT], 1u,
                                                    __ATOMIC_RELAXED, __HIP_MEMORY_SCOPE_AGENT);
                if (m == NGRP - 1) {
                    float tot = 0.0f;
#pragma unroll
                    for (int gg = 0; gg < NGRP; ++gg)
                        tot += __hip_atomic_load(&npart[(t * NGRP + gg) * SLOT],
                                                 __ATOMIC_RELAXED, __HIP_MEMORY_SCOPE_AGENT);
                    __hip_atomic_store(&go[t * SLOT], (tot < THRESH_SQ) ? 2u : 1u,
                                       __ATOMIC_RELAXED, __HIP_MEMORY_SCOPE_AGENT);
                }
            }
            unsigned v = 0;
            int guard = 0;
            do {
                v = __hip_atomic_load(&go[t * SLOT], __ATOMIC_RELAXED,
                                      __HIP_MEMORY_SCOPE_AGENT);
                if (v) break;
                __builtin_amdgcn_s_sleep(1);
            } while (++guard < (1 << 20));
            if (!v) v = 1u;
            asm volatile("" ::: "memory");   // compiler-only acquire
            s_go = v;
        }
        __syncthreads();

        if (s_go == 2u) {
            // converged at step t: final x = this step's output (exact per reference
            // freeze semantics). If it went to xB (t even), move own band to xA=d_out.
            if (!(t & 1)) {
                float4* A4 = (float4*)xA;
#pragma unroll
                for (int c = 0; c < NCHUNK; ++c)
                    A4[base + c * TPB + tid] = outv[c];
            }
            return;   // uniform across grid; no further barriers needed
        }
    }
}

extern "C" void kernel_launch(void* const* d_in, const int* in_sizes, int n_in,
                              void* d_out, int out_size, void* d_ws, size_t ws_size,
                              hipStream_t stream) {
    const float* img = (const float*)d_in[0];
    const int* seeds = (const int*)d_in[1];

    float2* xA = (float2*)d_out;                                // final buffer
    char* ws = (char*)d_ws;
    float2* xB = (float2*)ws;                                   // 8 MB
    unsigned* bar = (unsigned*)(ws + 8ull * 1024 * 1024);       // ~425 KB

    rw_init_kernel<<<NPAIRS / TPB, TPB, 0, stream>>>(seeds, xA, bar);
    rw_persist_kernel<<<NBLK, TPB, 0, stream>>>(img, seeds, xA, xB, bar);
}

// Round 6
// 981.832 us; speedup vs baseline: 3.3970x; 1.0193x over previous
//
#include <hip/hip_runtime.h>

typedef unsigned long long u64;

#define HH 1024
#define WW 1024
#define NPAIRS (HH * WW / 2)       // 524288 horizontal pixel pairs
#define TPB 256
#define NBLK 512                   // 2 blocks/CU via __launch_bounds__(256,2)
#define NCHUNK 4                   // band = 1024 pairs = 2 rows
#define NITER 100
#define BOUNDARY_F 0.1f
#define NFLAGS (NITER * NBLK)

union f2u { u64 u; float2 f; };

__device__ __forceinline__ float2 cld(const u64* p) {   // coherent (sc1) 8B load
    f2u t;
    t.u = __hip_atomic_load(p, __ATOMIC_RELAXED, __HIP_MEMORY_SCOPE_AGENT);
    return t.f;
}
__device__ __forceinline__ void cst(u64* p, float a, float b) {  // coherent 8B store
    f2u t; t.f = make_float2(a, b);
    __hip_atomic_store(p, t.u, __ATOMIC_RELAXED, __HIP_MEMORY_SCOPE_AGENT);
}

__device__ __forceinline__ float wfun(float c, float n, float valid) {
    float same = ((c > BOUNDARY_F) != (n > BOUNDARY_F)) ? 1.0f : 0.0f;
    return valid * __expf(-fabsf(c - n + same));
}

__global__ void rw_init_kernel(const int* __restrict__ seeds,
                               float2* __restrict__ xA,
                               unsigned* __restrict__ flags) {
    int P = blockIdx.x * blockDim.x + threadIdx.x;
    if (P < NPAIRS) {
        int2 s = ((const int2*)seeds)[P];
        float4 v;
        v.x = (s.x == 1) ? 1.0f : 0.0f;
        v.y = (s.x == 2) ? 1.0f : 0.0f;
        v.z = (s.y == 1) ? 1.0f : 0.0f;
        v.w = (s.y == 2) ? 1.0f : 0.0f;
        ((float4*)xA)[P] = v;
    }
    if (P < NFLAGS) flags[P] = 0u;
}

__launch_bounds__(TPB, 2)
__global__ void rw_persist_kernel(const float* __restrict__ img,
                                  const int* __restrict__ seeds,
                                  float2* __restrict__ xA,
                                  float2* __restrict__ xB,
                                  unsigned* __restrict__ flags) {
    const int tid = threadIdx.x;
    const int blk = blockIdx.x;
    const int band = ((blk & 7) << 6) | (blk >> 3);   // XCD swizzle: band±1 mostly same XCD
    const int base = band * (TPB * NCHUNK);           // first pair of band
    const int i0 = band * 2;                          // first row of band

    __shared__ float4 tile[2048];   // [0,1024) band, [1024,1536) up halo, [1536,2048) down halo

    // ---- precompute folded transition coefficients (iteration-invariant) ----
    float cf[NCHUNK][10];
    {
        const float2* img2 = (const float2*)img;
        const int2* seeds2 = (const int2*)seeds;
#pragma unroll
        for (int c = 0; c < NCHUNK; ++c) {
            const int P = base + c * TPB + tid;
            const int p = P * 2;
            const int i = p >> 10;
            const int j = p & 1023;
            const int uP = (i > 0) ? P - (WW / 2) : P;
            const int dP = (i < HH - 1) ? P + (WW / 2) : P;
            const int lp = (j > 0) ? p - 1 : p;
            const int rp = (j < WW - 2) ? p + 2 : p + 1;

            float2 cc = img2[P], iu = img2[uP], id = img2[dP];
            float il = img[lp], ir = img[rp];
            const float vU = (i > 0) ? 1.0f : 0.0f;
            const float vD = (i < HH - 1) ? 1.0f : 0.0f;
            const float vL = (j > 0) ? 1.0f : 0.0f;
            const float vR = (j < WW - 2) ? 1.0f : 0.0f;

            float w0u = wfun(cc.x, iu.x, vU), w0d = wfun(cc.x, id.x, vD);
            float w0l = wfun(cc.x, il, vL),   w0r = wfun(cc.x, cc.y, 1.0f);
            float rs0 = w0u + w0d + w0l + w0r;
            float inv0 = (rs0 > 0.0f) ? 1.0f / rs0 : 0.0f;
            float w1u = wfun(cc.y, iu.y, vU), w1d = wfun(cc.y, id.y, vD);
            float w1l = wfun(cc.y, cc.x, 1.0f), w1r = wfun(cc.y, ir, vR);
            float rs1 = w1u + w1d + w1l + w1r;
            float inv1 = (rs1 > 0.0f) ? 1.0f / rs1 : 0.0f;

            int2 s = seeds2[P];
            const bool m0 = s.x > 0, m1 = s.y > 0;
            cf[c][0] = m0 ? 0.0f : w0u * inv0;
            cf[c][1] = m0 ? 0.0f : w0d * inv0;
            cf[c][2] = m0 ? 0.0f : w0l * inv0;
            cf[c][3] = m0 ? 0.0f : w0r * inv0;
            cf[c][4] = m0 ? 1.0f : 0.0f;              // absorbing-seed self weight
            cf[c][5] = m1 ? 0.0f : w1u * inv1;
            cf[c][6] = m1 ? 0.0f : w1d * inv1;
            cf[c][7] = m1 ? 0.0f : w1l * inv1;
            cf[c][8] = m1 ? 0.0f : w1r * inv1;
            cf[c][9] = m1 ? 1.0f : 0.0f;
        }
    }

    for (int t = 0; t < NITER; ++t) {
        const float4* xin4 = (t & 1) ? (const float4*)xB : (const float4*)xA;
        float4*      xout4 = (t & 1) ? (float4*)xA : (float4*)xB;

        // ---- stage band + halo rows into LDS (coherent loads from L3) ----
#pragma unroll
        for (int c = 0; c < NCHUNK; ++c) {
            int bp = c * TPB + tid;
            const u64* src = (const u64*)(xin4 + base + bp);
            float2 lo = cld(src), hi = cld(src + 1);
            tile[bp] = make_float4(lo.x, lo.y, hi.x, hi.y);
        }
        {
            const int rup = (band == 0) ? 0 : i0 - 1;       // unused -> cf 0
            const int rdn = (band == NBLK - 1) ? HH - 1 : i0 + 2;
#pragma unroll
            for (int c2 = 0; c2 < 2; ++c2) {
                int hp = c2 * TPB + tid;                    // 0..511
                const u64* su = (const u64*)(xin4 + rup * 512 + hp);
                float2 lo = cld(su), hi = cld(su + 1);
                tile[1024 + hp] = make_float4(lo.x, lo.y, hi.x, hi.y);
                const u64* sd = (const u64*)(xin4 + rdn * 512 + hp);
                lo = cld(sd); hi = cld(sd + 1);
                tile[1536 + hp] = make_float4(lo.x, lo.y, hi.x, hi.y);
            }
        }
        __syncthreads();

        // ---- compute from LDS ----
        const float2* t2 = (const float2*)tile;
#pragma unroll
        for (int c = 0; c < NCHUNK; ++c) {
            const int bp = c * TPB + tid;
            const int r = bp >> 9;            // row within band
            const int jp = bp & 511;          // column pair
            float4 xc = tile[bp];
            float4 xu = r ? tile[jp] : tile[1024 + jp];
            float4 xd = r ? tile[1536 + jp] : tile[512 + jp];
            float2 xl = jp ? t2[2 * bp - 1] : t2[2 * bp];
            float2 xr = (jp < 511) ? t2[2 * bp + 2] : t2[2 * bp + 1];

            float4 out;
            out.x = cf[c][0]*xu.x + cf[c][1]*xd.x + cf[c][2]*xl.x + cf[c][3]*xc.z + cf[c][4]*xc.x;
            out.y = cf[c][0]*xu.y + cf[c][1]*xd.y + cf[c][2]*xl.y + cf[c][3]*xc.w + cf[c][4]*xc.y;
            out.z = cf[c][5]*xu.z + cf[c][6]*xd.z + cf[c][7]*xc.x + cf[c][8]*xr.x + cf[c][9]*xc.z;
            out.w = cf[c][5]*xu.w + cf[c][6]*xd.w + cf[c][7]*xc.y + cf[c][8]*xr.y + cf[c][9]*xc.w;

            if (t < NITER - 1) {
                u64* dst = (u64*)(xout4 + base + bp);
                cst(dst,     out.x, out.y);
                cst(dst + 1, out.z, out.w);
            } else {
                xout4[base + bp] = out;       // final: cached store, kernel-end flush
            }
        }

        if (t == NITER - 1) break;

        __syncthreads();   // compiler emits s_waitcnt vmcnt(0) before s_barrier:
                           // every wave's sc1 stores are at the coherence point.

        // ---- p2p neighbor sync: publish step t, wait for band±1's step t ----
        if (tid == 0) {
            __hip_atomic_store(&flags[t * NBLK + band], 1u,
                               __ATOMIC_RELAXED, __HIP_MEMORY_SCOPE_AGENT);
            bool need_u = (band > 0), need_d = (band < NBLK - 1);
            int guard = 0;
            while (need_u || need_d) {
                if (need_u &&
                    __hip_atomic_load(&flags[t * NBLK + band - 1], __ATOMIC_RELAXED,
                                      __HIP_MEMORY_SCOPE_AGENT)) need_u = false;
                if (need_d &&
                    __hip_atomic_load(&flags[t * NBLK + band + 1], __ATOMIC_RELAXED,
                                      __HIP_MEMORY_SCOPE_AGENT)) need_d = false;
                if (!(need_u || need_d)) break;
                __builtin_amdgcn_s_sleep(1);
                if (++guard > (1 << 20)) break;   // degrade, never hang
            }
            asm volatile("" ::: "memory");
        }
        __syncthreads();
    }
}

extern "C" void kernel_launch(void* const* d_in, const int* in_sizes, int n_in,
                              void* d_out, int out_size, void* d_ws, size_t ws_size,
                              hipStream_t stream) {
    const float* img = (const float*)d_in[0];
    const int* seeds = (const int*)d_in[1];

    float2* xA = (float2*)d_out;                                // final buffer
    char* ws = (char*)d_ws;
    float2* xB = (float2*)ws;                                   // 8 MB
    unsigned* flags = (unsigned*)(ws + 8ull * 1024 * 1024);     // 200 KB

    rw_init_kernel<<<NPAIRS / TPB, TPB, 0, stream>>>(seeds, xA, flags);
    rw_persist_kernel<<<NBLK, TPB, 0, stream>>>(img, seeds, xA, xB, flags);
}

// Round 7
// 477.953 us; speedup vs baseline: 6.9783x; 2.0542x over previous
//
#include <hip/hip_runtime.h>

typedef unsigned long long u64;

#define HH 1024
#define WW 1024
#define TPB 512
#define NBLK 256                   // 1 block/CU on 256 CUs -> co-resident
#define HROWS 4                    // rows per band
#define ROWP 512                   // float4 pixel-pairs per row
#define NITER 100
#define BOUNDARY_F 0.1f
#define FLAGS_N (NITER * NBLK)

union f2u { u64 u; float2 f; };

__device__ __forceinline__ float2 cld(const u64* p) {   // coherent (sc1) 8B load
    f2u t;
    t.u = __hip_atomic_load(p, __ATOMIC_RELAXED, __HIP_MEMORY_SCOPE_AGENT);
    return t.f;
}
__device__ __forceinline__ void cst(u64* p, float a, float b) {  // coherent 8B store
    f2u t; t.f = make_float2(a, b);
    __hip_atomic_store(p, t.u, __ATOMIC_RELAXED, __HIP_MEMORY_SCOPE_AGENT);
}

__device__ __forceinline__ float wfun(float c, float n, float valid) {
    float same = ((c > BOUNDARY_F) != (n > BOUNDARY_F)) ? 1.0f : 0.0f;
    return valid * __expf(-fabsf(c - n + same));
}

__global__ void rw_init_kernel(unsigned* __restrict__ flags) {
    int g = blockIdx.x * blockDim.x + threadIdx.x;
    if (g < FLAGS_N) flags[g] = 0u;
}

__launch_bounds__(TPB, 1)
__global__ void rw_persist_kernel(const float* __restrict__ img,
                                  const int* __restrict__ seeds,
                                  float4* __restrict__ out4,
                                  float4* __restrict__ haloT,   // [2][NBLK][ROWP] band top rows
                                  float4* __restrict__ haloB,   // [2][NBLK][ROWP] band bottom rows
                                  unsigned* __restrict__ flags) {
    const int tid = threadIdx.x;
    const int blk = blockIdx.x;
    const int band = ((blk & 7) << 5) | (blk >> 3);   // XCD swizzle: band±1 mostly same XCD
    const int i0 = band * HROWS;

    __shared__ float4 sband[HROWS][ROWP];             // 32 KB resident state

    // ---- iteration-invariant folded coefficients + x0 ----
    float cf[HROWS][10];
    float4 x0[HROWS];
    {
        const float2* img2 = (const float2*)img;
        const int2* seeds2 = (const int2*)seeds;
#pragma unroll
        for (int c = 0; c < HROWS; ++c) {
            const int i = i0 + c;
            const int P = i * ROWP + tid;             // pair index
            const int p = P * 2;
            const int j = p & (WW - 1);               // = 2*tid
            const int uP = (i > 0) ? P - ROWP : P;
            const int dP = (i < HH - 1) ? P + ROWP : P;
            const int lp = (j > 0) ? p - 1 : p;
            const int rp = (j < WW - 2) ? p + 2 : p + 1;

            float2 cc = img2[P], iu = img2[uP], id = img2[dP];
            float il = img[lp], ir = img[rp];
            const float vU = (i > 0) ? 1.0f : 0.0f;
            const float vD = (i < HH - 1) ? 1.0f : 0.0f;
            const float vL = (j > 0) ? 1.0f : 0.0f;
            const float vR = (j < WW - 2) ? 1.0f : 0.0f;

            float w0u = wfun(cc.x, iu.x, vU), w0d = wfun(cc.x, id.x, vD);
            float w0l = wfun(cc.x, il, vL),   w0r = wfun(cc.x, cc.y, 1.0f);
            float rs0 = w0u + w0d + w0l + w0r;
            float inv0 = (rs0 > 0.0f) ? 1.0f / rs0 : 0.0f;
            float w1u = wfun(cc.y, iu.y, vU), w1d = wfun(cc.y, id.y, vD);
            float w1l = wfun(cc.y, cc.x, 1.0f), w1r = wfun(cc.y, ir, vR);
            float rs1 = w1u + w1d + w1l + w1r;
            float inv1 = (rs1 > 0.0f) ? 1.0f / rs1 : 0.0f;

            int2 s = seeds2[P];
            const bool m0 = s.x > 0, m1 = s.y > 0;
            cf[c][0] = m0 ? 0.0f : w0u * inv0;
            cf[c][1] = m0 ? 0.0f : w0d * inv0;
            cf[c][2] = m0 ? 0.0f : w0l * inv0;
            cf[c][3] = m0 ? 0.0f : w0r * inv0;
            cf[c][4] = m0 ? 1.0f : 0.0f;              // absorbing-seed self weight
            cf[c][5] = m1 ? 0.0f : w1u * inv1;
            cf[c][6] = m1 ? 0.0f : w1d * inv1;
            cf[c][7] = m1 ? 0.0f : w1l * inv1;
            cf[c][8] = m1 ? 0.0f : w1r * inv1;
            cf[c][9] = m1 ? 1.0f : 0.0f;

            x0[c].x = (s.x == 1) ? 1.0f : 0.0f;
            x0[c].y = (s.x == 2) ? 1.0f : 0.0f;
            x0[c].z = (s.y == 1) ? 1.0f : 0.0f;
            x0[c].w = (s.y == 2) ? 1.0f : 0.0f;
        }
    }

    // ---- publish x0: LDS band + boundary rows to halo slot parity 0 ----
#pragma unroll
    for (int c = 0; c < HROWS; ++c) sband[c][tid] = x0[c];
    {
        u64* pt = (u64*)&haloT[band * ROWP + tid];          // parity 0
        cst(pt, x0[0].x, x0[0].y); cst(pt + 1, x0[0].z, x0[0].w);
        u64* pb = (u64*)&haloB[band * ROWP + tid];
        cst(pb, x0[HROWS - 1].x, x0[HROWS - 1].y);
        cst(pb + 1, x0[HROWS - 1].z, x0[HROWS - 1].w);
    }
    __syncthreads();                 // LDS visible + vmcnt(0): halo stores drained
    if (tid == 0)
        __hip_atomic_store(&flags[band], 1u, __ATOMIC_RELAXED,
                           __HIP_MEMORY_SCOPE_AGENT);

    const int bu = (band > 0) ? band - 1 : band;
    const int bd = (band < NBLK - 1) ? band + 1 : band;

    for (int s = 1; s <= NITER; ++s) {
        const int cur = (s - 1) & 1;
        const int nxt = s & 1;

        // ---- A: wait for neighbors' x_{s-1} halos (two waves poll in parallel) ----
        if (tid == 0 && band > 0) {
            int guard = 0;
            while (!__hip_atomic_load(&flags[(s - 1) * NBLK + band - 1],
                                      __ATOMIC_RELAXED, __HIP_MEMORY_SCOPE_AGENT)) {
                __builtin_amdgcn_s_sleep(1);
                if (++guard > (1 << 20)) break;
            }
        }
        if (tid == 64 && band < NBLK - 1) {
            int guard = 0;
            while (!__hip_atomic_load(&flags[(s - 1) * NBLK + band + 1],
                                      __ATOMIC_RELAXED, __HIP_MEMORY_SCOPE_AGENT)) {
                __builtin_amdgcn_s_sleep(1);
                if (++guard > (1 << 20)) break;
            }
        }
        __syncthreads();
        asm volatile("" ::: "memory");

        // ---- B: halo rows -> registers; compute stencil from LDS ----
        const u64* put = (const u64*)&haloB[(cur * NBLK + bu) * ROWP + tid];
        const u64* pdn = (const u64*)&haloT[(cur * NBLK + bd) * ROWP + tid];
        float2 t0 = cld(put), t1 = cld(put + 1);
        float2 b0 = cld(pdn), b1 = cld(pdn + 1);
        float4 htop = make_float4(t0.x, t0.y, t1.x, t1.y);
        float4 hbot = make_float4(b0.x, b0.y, b1.x, b1.y);

        float4 xc[HROWS], out[HROWS];
#pragma unroll
        for (int c = 0; c < HROWS; ++c) xc[c] = sband[c][tid];

#pragma unroll
        for (int c = 0; c < HROWS; ++c) {
            const float2* row2 = (const float2*)&sband[c][0];
            float2 xl = (tid > 0) ? row2[2 * tid - 1] : make_float2(xc[c].x, xc[c].y);
            float2 xr = (tid < ROWP - 1) ? row2[2 * tid + 2] : make_float2(xc[c].z, xc[c].w);
            float4 xu = (c == 0) ? htop : xc[c - 1];
            float4 xd = (c == HROWS - 1) ? hbot : xc[c + 1];

            out[c].x = cf[c][0]*xu.x + cf[c][1]*xd.x + cf[c][2]*xl.x + cf[c][3]*xc[c].z + cf[c][4]*xc[c].x;
            out[c].y = cf[c][0]*xu.y + cf[c][1]*xd.y + cf[c][2]*xl.y + cf[c][3]*xc[c].w + cf[c][4]*xc[c].y;
            out[c].z = cf[c][5]*xu.z + cf[c][6]*xd.z + cf[c][7]*xc[c].x + cf[c][8]*xr.x + cf[c][9]*xc[c].z;
            out[c].w = cf[c][5]*xu.w + cf[c][6]*xd.w + cf[c][7]*xc[c].y + cf[c][8]*xr.y + cf[c][9]*xc[c].w;
        }

        if (s < NITER) {
            // boundary rows of x_s -> halo slot parity nxt (coherent)
            u64* pt = (u64*)&haloT[(nxt * NBLK + band) * ROWP + tid];
            cst(pt, out[0].x, out[0].y); cst(pt + 1, out[0].z, out[0].w);
            u64* pb = (u64*)&haloB[(nxt * NBLK + band) * ROWP + tid];
            cst(pb, out[HROWS - 1].x, out[HROWS - 1].y);
            cst(pb + 1, out[HROWS - 1].z, out[HROWS - 1].w);

            __syncthreads();         // all LDS reads of old band done + sc1 stores drained

            // LDS writeback (visible to next iter via next iter's barrier)
#pragma unroll
            for (int c = 0; c < HROWS; ++c) sband[c][tid] = out[c];
            if (tid == 0)
                __hip_atomic_store(&flags[s * NBLK + band], 1u,
                                   __ATOMIC_RELAXED, __HIP_MEMORY_SCOPE_AGENT);
        } else {
            // final step: write x_100 band straight to d_out (cached stores)
#pragma unroll
            for (int c = 0; c < HROWS; ++c)
                out4[(i0 + c) * ROWP + tid] = out[c];
        }
    }
}

extern "C" void kernel_launch(void* const* d_in, const int* in_sizes, int n_in,
                              void* d_out, int out_size, void* d_ws, size_t ws_size,
                              hipStream_t stream) {
    const float* img = (const float*)d_in[0];
    const int* seeds = (const int*)d_in[1];

    float4* out4 = (float4*)d_out;
    char* ws = (char*)d_ws;
    float4* haloT = (float4*)ws;                                  // 4 MB [2][256][512]
    float4* haloB = (float4*)(ws + 4ull * 1024 * 1024);           // 4 MB
    unsigned* flags = (unsigned*)(ws + 8ull * 1024 * 1024);       // 100 KB

    rw_init_kernel<<<(FLAGS_N + 255) / 256, 256, 0, stream>>>(flags);
    rw_persist_kernel<<<NBLK, TPB, 0, stream>>>(img, seeds, out4, haloT, haloB, flags);
}

// Round 8
// 329.342 us; speedup vs baseline: 10.1272x; 1.4512x over previous
//
#include <hip/hip_runtime.h>

typedef unsigned long long u64;
typedef __attribute__((ext_vector_type(4))) float f32x4;

#define HH 1024
#define WW 1024
#define TPB 512
#define NBLK 256                   // 1 block/CU -> co-resident
#define BROWS 4                    // rows per band
#define ROWP 512                   // float4 pixel-pairs per row
#define NSYNC 50                   // 2 Jacobi steps per sync
#define BOUNDARY_F 0.1f
#define FLAGS_N (NSYNC * NBLK)

union f2u { u64 u; float2 f; };
union v4u { float4 f; f32x4 v; };

__device__ __forceinline__ float2 cld(const u64* p) {   // coherent 8B load
    f2u t;
    t.u = __hip_atomic_load(p, __ATOMIC_RELAXED, __HIP_MEMORY_SCOPE_AGENT);
    return t.f;
}

// coherent 16B store: one fabric transaction, bypasses non-coherent L2
__device__ __forceinline__ void cst16(float4* base, int elem, float4 val) {
    v4u t; t.f = val;
    asm volatile("global_store_dwordx4 %0, %1, %2 sc0 sc1"
                 :: "v"(elem * 16), "v"(t.v), "s"(base) : "memory");
}

__device__ __forceinline__ float wfun(float c, float n, float valid) {
    float same = ((c > BOUNDARY_F) != (n > BOUNDARY_F)) ? 1.0f : 0.0f;
    return valid * __expf(-fabsf(c - n + same));
}

// one row-pair Jacobi update from folded coefficients
__device__ __forceinline__ float4 stepr(const float* cf, float4 xc, float4 xu,
                                        float4 xd, float2 xl, float2 xr) {
    float4 o;
    o.x = cf[0]*xu.x + cf[1]*xd.x + cf[2]*xl.x + cf[3]*xc.z + cf[4]*xc.x;
    o.y = cf[0]*xu.y + cf[1]*xd.y + cf[2]*xl.y + cf[3]*xc.w + cf[4]*xc.y;
    o.z = cf[5]*xu.z + cf[6]*xd.z + cf[7]*xc.x + cf[8]*xr.x + cf[9]*xc.z;
    o.w = cf[5]*xu.w + cf[6]*xd.w + cf[7]*xc.y + cf[8]*xr.y + cf[9]*xc.w;
    return o;
}

__device__ __forceinline__ void horiz(const float4* row, int tid, float4 xc,
                                      float2* xl, float2* xr) {
    const float2* r2 = (const float2*)row;
    *xl = (tid > 0) ? r2[2 * tid - 1] : make_float2(xc.x, xc.y);
    *xr = (tid < ROWP - 1) ? r2[2 * tid + 2] : make_float2(xc.z, xc.w);
}

__global__ void rw_init_kernel(unsigned* __restrict__ flags) {
    int g = blockIdx.x * blockDim.x + threadIdx.x;
    if (g < FLAGS_N) flags[g] = 0u;
}

__launch_bounds__(TPB)
__global__ void rw_persist_kernel(const float* __restrict__ img,
                                  const int* __restrict__ seeds,
                                  float4* __restrict__ par0,   // = d_out, natural layout
                                  float4* __restrict__ par1,   // ws, natural layout
                                  unsigned* __restrict__ flags) {
    const int tid = threadIdx.x;
    const int blk = blockIdx.x;
    const int band = ((blk & 7) << 5) | (blk >> 3);   // XCD swizzle (perf only)
    const int i0 = band * BROWS;

    __shared__ float4 sband[BROWS][ROWP];   // 32 KB resident band
    __shared__ float4 sgU[ROWP];            // ghost row i0-1 (for horizontals)
    __shared__ float4 sgD[ROWP];            // ghost row i0+4

    // ---- coefficients for rows i0-1 .. i0+4 (L=0..5); ghost rows may be
    // garbage-but-finite (their contributions are weighted by 0 where it matters)
    float cf[6][10];
    float4 x0[BROWS];
    {
        const float2* img2 = (const float2*)img;
        const int2* seeds2 = (const int2*)seeds;
#pragma unroll
        for (int L = 0; L < 6; ++L) {
            const int gi = i0 - 1 + L;
            const int g = min(max(gi, 0), HH - 1);
            const int P = g * ROWP + tid;
            const int p = P * 2;
            const int j = p & (WW - 1);
            const int uP = (g > 0) ? P - ROWP : P;
            const int dP = (g < HH - 1) ? P + ROWP : P;
            const int lp = (j > 0) ? p - 1 : p;
            const int rp = (j < WW - 2) ? p + 2 : p + 1;

            float2 cc = img2[P], iu = img2[uP], id = img2[dP];
            float il = img[lp], ir = img[rp];
            const float vU = (g > 0) ? 1.0f : 0.0f;
            const float vD = (g < HH - 1) ? 1.0f : 0.0f;
            const float vL = (j > 0) ? 1.0f : 0.0f;
            const float vR = (j < WW - 2) ? 1.0f : 0.0f;

            float w0u = wfun(cc.x, iu.x, vU), w0d = wfun(cc.x, id.x, vD);
            float w0l = wfun(cc.x, il, vL),   w0r = wfun(cc.x, cc.y, 1.0f);
            float rs0 = w0u + w0d + w0l + w0r;
            float inv0 = (rs0 > 0.0f) ? 1.0f / rs0 : 0.0f;
            float w1u = wfun(cc.y, iu.y, vU), w1d = wfun(cc.y, id.y, vD);
            float w1l = wfun(cc.y, cc.x, 1.0f), w1r = wfun(cc.y, ir, vR);
            float rs1 = w1u + w1d + w1l + w1r;
            float inv1 = (rs1 > 0.0f) ? 1.0f / rs1 : 0.0f;

            int2 s = seeds2[P];
            const bool m0 = s.x > 0, m1 = s.y > 0;
            cf[L][0] = m0 ? 0.0f : w0u * inv0;
            cf[L][1] = m0 ? 0.0f : w0d * inv0;
            cf[L][2] = m0 ? 0.0f : w0l * inv0;
            cf[L][3] = m0 ? 0.0f : w0r * inv0;
            cf[L][4] = m0 ? 1.0f : 0.0f;          // absorbing-seed self weight
            cf[L][5] = m1 ? 0.0f : w1u * inv1;
            cf[L][6] = m1 ? 0.0f : w1d * inv1;
            cf[L][7] = m1 ? 0.0f : w1l * inv1;
            cf[L][8] = m1 ? 0.0f : w1r * inv1;
            cf[L][9] = m1 ? 1.0f : 0.0f;

            if (L >= 1 && L <= 4) {
                float4 v;
                v.x = (s.x == 1) ? 1.0f : 0.0f;
                v.y = (s.x == 2) ? 1.0f : 0.0f;
                v.z = (s.y == 1) ? 1.0f : 0.0f;
                v.w = (s.y == 2) ? 1.0f : 0.0f;
                x0[L - 1] = v;
            }
        }
    }

    // ---- publish x0 (parity 0 = d_out, natural layout) ----
#pragma unroll
    for (int c = 0; c < BROWS; ++c) {
        sband[c][tid] = x0[c];
        cst16(par0, (i0 + c) * ROWP + tid, x0[c]);
    }
    __syncthreads();                 // LDS visible + vmcnt(0): stores at coherence pt
    if (tid == 0)
        __hip_atomic_store(&flags[band], 1u, __ATOMIC_RELAXED,
                           __HIP_MEMORY_SCOPE_AGENT);

    const int rU0 = max(i0 - 2, 0), rU1 = max(i0 - 1, 0);
    const int rD0 = min(i0 + 4, HH - 1), rD1 = min(i0 + 5, HH - 1);

    for (int m = 0; m < NSYNC; ++m) {
        // ---- poll neighbors' x_{2m} flags (two waves in parallel) ----
        if (tid == 0 && band > 0) {
            int guard = 0;
            while (!__hip_atomic_load(&flags[m * NBLK + band - 1],
                                      __ATOMIC_RELAXED, __HIP_MEMORY_SCOPE_AGENT)) {
                __builtin_amdgcn_s_sleep(1);
                if (++guard > (1 << 20)) break;
            }
        }
        if (tid == 64 && band < NBLK - 1) {
            int guard = 0;
            while (!__hip_atomic_load(&flags[m * NBLK + band + 1],
                                      __ATOMIC_RELAXED, __HIP_MEMORY_SCOPE_AGENT)) {
                __builtin_amdgcn_s_sleep(1);
                if (++guard > (1 << 20)) break;
            }
        }
        __syncthreads();                      // [A]
        asm volatile("" ::: "memory");

        const float4* pin = (m & 1) ? par1 : par0;

        // ---- issue 2-deep ghost loads (coherent) ----
        const u64* pu0 = (const u64*)(pin + rU0 * ROWP + tid);
        const u64* pu1 = (const u64*)(pin + rU1 * ROWP + tid);
        const u64* pd0 = (const u64*)(pin + rD0 * ROWP + tid);
        const u64* pd1 = (const u64*)(pin + rD1 * ROWP + tid);
        float2 a0 = cld(pu0), a1 = cld(pu0 + 1);
        float2 b0 = cld(pu1), b1 = cld(pu1 + 1);
        float2 c0 = cld(pd0), c1 = cld(pd0 + 1);
        float2 d0 = cld(pd1), d1 = cld(pd1 + 1);

        float4 xcO[BROWS];
#pragma unroll
        for (int c = 0; c < BROWS; ++c) xcO[c] = sband[c][tid];

        // ---- step 1, interior rows (v=1,2) while ghost loads fly ----
        float4 y[6];
        {
            float2 xl, xr;
            horiz(&sband[1][0], tid, xcO[1], &xl, &xr);
            y[2] = stepr(cf[2], xcO[1], xcO[0], xcO[2], xl, xr);
            horiz(&sband[2][0], tid, xcO[2], &xl, &xr);
            y[3] = stepr(cf[3], xcO[2], xcO[1], xcO[3], xl, xr);
        }

        float4 U0 = make_float4(a0.x, a0.y, a1.x, a1.y);
        float4 U1 = make_float4(b0.x, b0.y, b1.x, b1.y);
        float4 D0 = make_float4(c0.x, c0.y, c1.x, c1.y);
        float4 D1 = make_float4(d0.x, d0.y, d1.x, d1.y);
        sgU[tid] = U1;
        sgD[tid] = D0;
        __syncthreads();                      // [B]

        // ---- step 1, ghost-dependent rows (v=-1,0,3,4) ----
        {
            float2 xl, xr;
            horiz(&sgU[0], tid, U1, &xl, &xr);
            y[0] = stepr(cf[0], U1, U0, xcO[0], xl, xr);
            horiz(&sband[0][0], tid, xcO[0], &xl, &xr);
            y[1] = stepr(cf[1], xcO[0], U1, xcO[1], xl, xr);
            horiz(&sband[3][0], tid, xcO[3], &xl, &xr);
            y[4] = stepr(cf[4], xcO[3], xcO[2], D0, xl, xr);
            horiz(&sgD[0], tid, D0, &xl, &xr);
            y[5] = stepr(cf[5], D0, xcO[3], D1, xl, xr);
        }
        __syncthreads();                      // [C] all x reads done
#pragma unroll
        for (int c = 0; c < BROWS; ++c) sband[c][tid] = y[c + 1];
        __syncthreads();                      // [D]

        // ---- step 2, own rows (v=0..3) ----
        float4 out[BROWS];
#pragma unroll
        for (int c = 0; c < BROWS; ++c) {
            float2 xl, xr;
            horiz(&sband[c][0], tid, y[c + 1], &xl, &xr);
            out[c] = stepr(cf[c + 1], y[c + 1], y[c], y[c + 2], xl, xr);
        }

        if (m == NSYNC - 1) {
            // final publish = x_100 into parity 0 = d_out (plain cached stores)
#pragma unroll
            for (int c = 0; c < BROWS; ++c)
                par0[(i0 + c) * ROWP + tid] = out[c];
            break;
        }

        __syncthreads();                      // [E] y reads done
        float4* pout = (m & 1) ? par0 : par1;
#pragma unroll
        for (int c = 0; c < BROWS; ++c) {
            sband[c][tid] = out[c];
            cst16(pout, (i0 + c) * ROWP + tid, out[c]);
        }
        __syncthreads();                      // [F] LDS visible + stores drained
        if (tid == 0)
            __hip_atomic_store(&flags[(m + 1) * NBLK + band], 1u,
                               __ATOMIC_RELAXED, __HIP_MEMORY_SCOPE_AGENT);
    }
}

extern "C" void kernel_launch(void* const* d_in, const int* in_sizes, int n_in,
                              void* d_out, int out_size, void* d_ws, size_t ws_size,
                              hipStream_t stream) {
    const float* img = (const float*)d_in[0];
    const int* seeds = (const int*)d_in[1];

    float4* par0 = (float4*)d_out;                              // parity 0 + final
    char* ws = (char*)d_ws;
    float4* par1 = (float4*)ws;                                 // 8 MB parity 1
    unsigned* flags = (unsigned*)(ws + 8ull * 1024 * 1024);     // 50 KB

    rw_init_kernel<<<(FLAGS_N + 255) / 256, 256, 0, stream>>>(flags);
    rw_persist_kernel<<<NBLK, TPB, 0, stream>>>(img, seeds, par0, par1, flags);
}